// Round 5
// baseline (25752.280 us; speedup 1.0000x reference)
//
#include <hip/hip_runtime.h>
#include <math.h>

#define BATCH 64
#define PIX   196
#define ENCD  2048
#define DECD  512
#define ATTD  512
#define EMBD  512
#define VOC   10000
#define VOCP  10240
#define LCAP  52
#define TSTEPS 51
#define XHDIM 3072   // emb(512) | gated awe(2048) | h(512)
#define AGDIM 2560   // att2(512) | gate(2048)
#define NBLK  256    // persistent grid
#define NTHR  512

typedef short v8s __attribute__((ext_vector_type(8)));
typedef float v4f __attribute__((ext_vector_type(4)));

__device__ __forceinline__ float bf2f(unsigned short u) {
    union { unsigned int i; float f; } x; x.i = ((unsigned int)u) << 16; return x.f;
}
__device__ __forceinline__ unsigned short f2bf(float f) {
    union { float f; unsigned int i; } x; x.f = f;
    unsigned int r = x.i + 0x7fffu + ((x.i >> 16) & 1u);
    return (unsigned short)(r >> 16);
}
__device__ __forceinline__ float sigf(float x) { return 1.f / (1.f + __expf(-x)); }

// ---------------- setup: argsort + int outputs + zero barrier ----------------
__global__ void k_setup(const int* caps, const int* lens,
                        int* order, int* declen, int* bar,
                        float* caps_out, float* declen_out, float* order_out) {
    __shared__ int sl[64];
    __shared__ int so[64];
    int tid = threadIdx.x;
    if (tid < 2) bar[tid] = 0;
    sl[tid] = lens[tid];
    __syncthreads();
    int li = sl[tid];
    int pos = 0;
    for (int j = 0; j < 64; ++j) {
        int lj = sl[j];
        if (lj > li || (lj == li && j < tid)) pos++;
    }
    so[pos] = tid;
    __syncthreads();
    int ob = so[tid];
    order[tid] = ob;
    int dl = sl[ob] - 1;
    declen[tid] = dl;
    order_out[tid] = (float)ob;
    declen_out[tid] = (float)dl;
    for (int l = 0; l < LCAP; ++l)
        caps_out[tid * LCAP + l] = (float)caps[ob * LCAP + l];
}

// ---------------- tiled transpose fp32 -> bf16: D[n][k] = S[k][n] (zero-fill) ----------------
__global__ __launch_bounds__(256) void k_tr(const float* S, int K, int N,
                                            unsigned short* D, int Nout) {
    __shared__ float t[64][65];
    int n0 = blockIdx.x * 64, k0 = blockIdx.y * 64, tid = threadIdx.x;
    for (int idx = tid; idx < 4096; idx += 256) {
        int r = idx >> 6, c = idx & 63;
        int k = k0 + r, n = n0 + c;
        t[r][c] = (k < K && n < N) ? S[(size_t)k * N + n] : 0.f;
    }
    __syncthreads();
    for (int idx = tid; idx < 4096; idx += 256) {
        int r = idx >> 6, c = idx & 63;
        int n = n0 + r, k = k0 + c;
        if (n < Nout && k < K) D[(size_t)n * K + k] = f2bf(t[c][r]);
    }
}

// Wcomb[j][k] = k<2560 ? Wih[j][k] : Whh[j][k-2560]   (bf16, 2048x3072, k-contig)
__global__ void k_cvt_comb(const float* Wih, const float* Whh, unsigned short* W) {
    int j = blockIdx.x, tid = threadIdx.x;
    for (int k = tid * 4; k < XHDIM; k += 1024) {
        const float* src = (k < 2560) ? (Wih + (size_t)j * 2560 + k)
                                      : (Whh + (size_t)j * 512 + (k - 2560));
        float4 v = *(const float4*)src;
        ushort4 o;
        o.x = f2bf(v.x); o.y = f2bf(v.y); o.z = f2bf(v.z); o.w = f2bf(v.w);
        *(ushort4*)(W + (size_t)j * XHDIM + k) = o;
    }
}

// enc_bf[b][p][c] = bf16(enc[order[b]][p][c])
__global__ void k_cvt_enc(const float* enc, const int* order, unsigned short* enc_bf) {
    int b = blockIdx.x, p = blockIdx.y, tid = threadIdx.x;
    const float* src = enc + ((size_t)order[b] * PIX + p) * ENCD + tid * 8;
    float4 v0 = *(const float4*)src;
    float4 v1 = *(const float4*)(src + 4);
    unsigned short o[8];
    o[0] = f2bf(v0.x); o[1] = f2bf(v0.y); o[2] = f2bf(v0.z); o[3] = f2bf(v0.w);
    o[4] = f2bf(v1.x); o[5] = f2bf(v1.y); o[6] = f2bf(v1.z); o[7] = f2bf(v1.w);
    *(uint4*)(enc_bf + ((size_t)b * PIX + p) * ENCD + tid * 8) = *(uint4*)o;
}

// ---------------- mean over pixels (sorted order) ----------------
__global__ void k_mean(const float* enc, const int* order, float* meanv) {
    int b = blockIdx.x;
    int col = blockIdx.y * 256 + threadIdx.x;
    int ob = order[b];
    const float* base = enc + (size_t)ob * PIX * ENCD + col;
    float acc = 0.f;
    for (int p = 0; p < PIX; ++p) acc += base[(size_t)p * ENCD];
    meanv[b * ENCD + col] = acc * (1.0f / (float)PIX);
}

// ---------------- h0/c0 tiled GEMM (fp32 VALU, one-time) ----------------
__global__ __launch_bounds__(256) void k_h0c0(const float* meanv,
                                              const float* WH, const float* bH,
                                              const float* WC, const float* bC,
                                              float* c_f32, unsigned short* hnext,
                                              unsigned short* xh) {
    __shared__ float As[64 * 33];
    __shared__ float Bs[32 * 65];
    int nt = blockIdx.x, tid = threadIdx.x;
    const float* W; const float* bias; int j0; bool isH;
    if (nt < 8) { W = WH; bias = bH; j0 = nt * 64; isH = true; }
    else        { W = WC; bias = bC; j0 = (nt - 8) * 64; isH = false; }
    float acc[4][4] = {};
    int tr = tid & 15, tc = tid >> 4;
    for (int k0 = 0; k0 < ENCD; k0 += 32) {
        for (int idx = tid; idx < 512; idx += 256) {
            int rl = idx >> 3, k4 = (idx & 7) << 2;
            float4 v = *(const float4*)(meanv + (size_t)rl * ENCD + k0 + k4);
            float* d = As + rl * 33 + k4;
            d[0] = v.x; d[1] = v.y; d[2] = v.z; d[3] = v.w;
        }
        for (int idx = tid; idx < 512; idx += 256) {
            int k = idx >> 4, j4 = (idx & 15) << 2;
            float4 v = *(const float4*)(W + (size_t)(k0 + k) * DECD + j0 + j4);
            float* d = Bs + k * 65 + j4;
            d[0] = v.x; d[1] = v.y; d[2] = v.z; d[3] = v.w;
        }
        __syncthreads();
        for (int kk = 0; kk < 32; ++kk) {
            float a[4], bb[4];
            for (int i = 0; i < 4; ++i) a[i] = As[(tr * 4 + i) * 33 + kk];
            for (int i = 0; i < 4; ++i) bb[i] = Bs[kk * 65 + tc * 4 + i];
            for (int i = 0; i < 4; ++i)
                for (int j2 = 0; j2 < 4; ++j2) acc[i][j2] += a[i] * bb[j2];
        }
        __syncthreads();
    }
    for (int i = 0; i < 4; ++i)
        for (int j2 = 0; j2 < 4; ++j2) {
            int r = tr * 4 + i, j = j0 + tc * 4 + j2;
            float v = acc[i][j2] + bias[j];
            if (isH) {
                hnext[(size_t)r * DECD + j] = f2bf(v);
                xh[(size_t)r * XHDIM + 2560 + j] = f2bf(v);
            } else {
                c_f32[(size_t)r * DECD + j] = v;
            }
        }
}

// ---------------- att1 (MFMA): att1bf = enc_bf @ attWT^T + b  (12544x512, K=2048) ----------------
__global__ __launch_bounds__(256) void k_att1(const unsigned short* enc_bf,
                                              const unsigned short* attWT,
                                              const float* bias,
                                              unsigned short* att1bf) {
    int m0 = blockIdx.x * 256, n0 = blockIdx.y * 64, tid = threadIdx.x;
    int w = tid >> 6, l = tid & 63;
    int col = l & 15, kq = l >> 4;
    v4f acc[4][4];
    for (int a = 0; a < 4; ++a) for (int s = 0; s < 4; ++s) acc[a][s] = (v4f){0.f,0.f,0.f,0.f};
    for (int kk = 0; kk < 64; ++kk) {
        int k = kk * 32 + kq * 8;
        v8s af[4], bf[4];
#pragma unroll
        for (int mm = 0; mm < 4; ++mm)
            af[mm] = *(const v8s*)(enc_bf + (size_t)(m0 + (w * 4 + mm) * 16 + col) * ENCD + k);
#pragma unroll
        for (int ss = 0; ss < 4; ++ss)
            bf[ss] = *(const v8s*)(attWT + (size_t)(n0 + ss * 16 + col) * ENCD + k);
#pragma unroll
        for (int mm = 0; mm < 4; ++mm)
#pragma unroll
            for (int ss = 0; ss < 4; ++ss)
                acc[mm][ss] = __builtin_amdgcn_mfma_f32_16x16x32_bf16(af[mm], bf[ss], acc[mm][ss], 0, 0, 0);
    }
#pragma unroll
    for (int mm = 0; mm < 4; ++mm)
#pragma unroll
        for (int ss = 0; ss < 4; ++ss) {
            int n = n0 + ss * 16 + col;
            float bv = bias[n];
#pragma unroll
            for (int r = 0; r < 4; ++r) {
                int m = m0 + (w * 4 + mm) * 16 + kq * 4 + r;
                att1bf[(size_t)m * ATTD + n] = f2bf(acc[mm][ss][r] + bv);
            }
        }
}

// ---------------- persistent scan kernel ----------------
struct ScanArgs {
    const unsigned short *WagT, *Wcomb, *att1bf, *enc_bf;
    const float *bad, *bfb, *wfull, *bfull, *bih, *bhh, *embW;
    const int *caps, *order, *declen;
    unsigned short *hnext, *xh, *hallbf;
    float *att2, *gate, *c;
    float *alphas_out;
    int *bar;
};

__device__ __forceinline__ void gbar(int* bar) {
    __syncthreads();
    __threadfence();
    if (threadIdx.x == 0) {
        int* cnt = bar;
        int* gen = bar + 1;
        int g = __hip_atomic_load(gen, __ATOMIC_RELAXED, __HIP_MEMORY_SCOPE_AGENT);
        int prev = __hip_atomic_fetch_add(cnt, 1, __ATOMIC_ACQ_REL, __HIP_MEMORY_SCOPE_AGENT);
        if (prev == NBLK - 1) {
            __hip_atomic_store(cnt, 0, __ATOMIC_RELAXED, __HIP_MEMORY_SCOPE_AGENT);
            __hip_atomic_fetch_add(gen, 1, __ATOMIC_ACQ_REL, __HIP_MEMORY_SCOPE_AGENT);
        } else {
            while (__hip_atomic_load(gen, __ATOMIC_ACQUIRE, __HIP_MEMORY_SCOPE_AGENT) == g)
                __builtin_amdgcn_s_sleep(1);
        }
    }
    __syncthreads();
    __threadfence();
}

__global__ __launch_bounds__(NTHR, 1) void k_scan(ScanArgs A) {
    __shared__ float smem[5632];                 // P_A: 1K, P_B: 5.6K
    __shared__ unsigned short sA[64 * 520];      // P_C A-stage (65 KB)
    __shared__ float gbuf[64 * 32];              // P_C gate exchange (8 KB)
    const int bid = blockIdx.x;
    const int tid = threadIdx.x;
    const int w = tid >> 6, l = tid & 63;
    const int col = l & 15, kq = l >> 4;

    for (int t = 0; t < TSTEPS; ++t) {
        // ======== P_A: att2|gate GEMM (MFMA) + emb + h->xh copy ========
        if (bid < 160) {
            int n0 = bid * 16;
            int ms = w & 3, kh = w >> 2;
            v4f acc = (v4f){0.f, 0.f, 0.f, 0.f};
            for (int kk = 0; kk < 8; ++kk) {
                int k = kh * 256 + kk * 32 + kq * 8;
                v8s af = *(const v8s*)(A.hnext + (size_t)(ms * 16 + col) * DECD + k);
                v8s bf = *(const v8s*)(A.WagT + (size_t)(n0 + col) * DECD + k);
                acc = __builtin_amdgcn_mfma_f32_16x16x32_bf16(af, bf, acc, 0, 0, 0);
            }
            if (kh == 1) {
#pragma unroll
                for (int r = 0; r < 4; ++r) smem[(ms * 64 + l) * 4 + r] = acc[r];
            }
            __syncthreads();
            if (kh == 0) {
                int n = n0 + col;
#pragma unroll
                for (int r = 0; r < 4; ++r) {
                    float v = acc[r] + smem[(ms * 64 + l) * 4 + r];
                    int b = ms * 16 + kq * 4 + r;
                    if (n < 512) A.att2[b * ATTD + n] = v + A.bad[n];
                    else A.gate[b * ENCD + (n - 512)] = sigf(v + A.bfb[n - 512]);
                }
            }
        } else if (bid < 224) {
            int b = bid - 160;
            int tok = A.caps[A.order[b] * LCAP + t];
            if (tid < 512)
                A.xh[(size_t)b * XHDIM + tid] = f2bf(A.embW[(size_t)tok * EMBD + tid]);
        } else {
            int b = (bid - 224) * 2 + (tid >> 8);
            int dd = (tid & 255) * 2;
            *(unsigned int*)(A.xh + (size_t)b * XHDIM + 2560 + dd) =
                *(const unsigned int*)(A.hnext + (size_t)b * DECD + dd);
        }
        gbar(A.bar);

        // ======== P_B: e + softmax + awe + gated-x (2 blocks/batch) ========
        if (bid < 128) {
            int b = bid >> 1, half = bid & 1;
            float* a2s = smem;
            float* wfs = smem + 512;
            float* sal = smem + 1024;
            float* red = smem + 1280;
            float* sacc = smem + 1536;   // 4096
            if (tid < 512) { a2s[tid] = A.att2[b * ATTD + tid]; wfs[tid] = A.wfull[tid]; }
            __syncthreads();
            for (int p = w; p < PIX; p += 8) {
                uint4 v = *(const uint4*)(A.att1bf + ((size_t)b * PIX + p) * ATTD + l * 8);
                const unsigned short* us = (const unsigned short*)&v;
                float acc = 0.f;
#pragma unroll
                for (int jj = 0; jj < 8; ++jj) {
                    int a = l * 8 + jj;
                    float x = bf2f(us[jj]) + a2s[a];
                    acc += fmaxf(x, 0.f) * wfs[a];
                }
                for (int off = 32; off; off >>= 1) acc += __shfl_down(acc, off);
                if (l == 0) sal[p] = acc;
            }
            __syncthreads();
            float ev = -1e30f, pv = 0.f;
            if (tid < 256) { ev = (tid < PIX) ? sal[tid] + A.bfull[0] : -1e30f; red[tid] = ev; }
            __syncthreads();
            for (int s = 128; s; s >>= 1) { if (tid < s) red[tid] = fmaxf(red[tid], red[tid + s]); __syncthreads(); }
            float m = red[0];
            __syncthreads();
            if (tid < 256) { pv = (tid < PIX) ? __expf(ev - m) : 0.f; red[tid] = pv; }
            __syncthreads();
            for (int s = 128; s; s >>= 1) { if (tid < s) red[tid] += red[tid + s]; __syncthreads(); }
            float inv = 1.f / red[0];
            __syncthreads();
            if (tid < PIX) {
                float al = pv * inv;
                sal[tid] = al;
                if (half == 0)
                    A.alphas_out[((size_t)b * TSTEPS + t) * PIX + tid] =
                        (t < A.declen[b]) ? al : 0.f;
            }
            __syncthreads();
            int pg = tid >> 7, cg = tid & 127;
            int col0 = half * 1024 + cg * 8;
            float acc8[8] = {};
            const unsigned short* base = A.enc_bf + (size_t)b * PIX * ENCD + col0;
            for (int p = pg; p < PIX; p += 4) {
                uint4 v = *(const uint4*)(base + (size_t)p * ENCD);
                const unsigned short* us = (const unsigned short*)&v;
                float a = sal[p];
#pragma unroll
                for (int jj = 0; jj < 8; ++jj) acc8[jj] += a * bf2f(us[jj]);
            }
#pragma unroll
            for (int jj = 0; jj < 8; ++jj) sacc[pg * 1024 + cg * 8 + jj] = acc8[jj];
            __syncthreads();
            int cl = tid * 2;
            float s0 = sacc[cl] + sacc[1024 + cl] + sacc[2048 + cl] + sacc[3072 + cl];
            float s1 = sacc[cl + 1] + sacc[1024 + cl + 1] + sacc[2048 + cl + 1] + sacc[3072 + cl + 1];
            int gc = half * 1024 + cl;
            float g0 = A.gate[b * ENCD + gc], g1 = A.gate[b * ENCD + gc + 1];
            unsigned int o = (unsigned int)f2bf(g0 * s0) | ((unsigned int)f2bf(g1 * s1) << 16);
            *(unsigned int*)(A.xh + (size_t)b * XHDIM + EMBD + gc) = o;
        }
        gbar(A.bar);

        // ======== P_C: gates GEMM (MFMA) + LSTM update ========
        if (bid < 64) {
            int d0 = bid * 8;
            int ms = w & 3, ns = w >> 2;
            int gi = ns * 2 + (col >> 3);
            int j = gi * 512 + d0 + (col & 7);
            v4f acc = (v4f){0.f, 0.f, 0.f, 0.f};
            const unsigned short* Brow = A.Wcomb + (size_t)j * XHDIM;
            for (int ch = 0; ch < 6; ++ch) {
                int kc0 = ch * 512;
                // stage xh chunk [64][512] -> LDS (pad to 520)
                for (int u = tid; u < 4096; u += NTHR) {
                    int row = u >> 6, c8 = (u & 63) * 8;
                    *(uint4*)(sA + (size_t)row * 520 + c8) =
                        *(const uint4*)(A.xh + (size_t)row * XHDIM + kc0 + c8);
                }
                __syncthreads();
                const unsigned short* Arow = sA + (size_t)(ms * 16 + col) * 520;
#pragma unroll
                for (int kk = 0; kk < 16; ++kk) {
                    int k = kk * 32 + kq * 8;
                    v8s af = *(const v8s*)(Arow + k);
                    v8s bf = *(const v8s*)(Brow + kc0 + k);
                    acc = __builtin_amdgcn_mfma_f32_16x16x32_bf16(af, bf, acc, 0, 0, 0);
                }
                __syncthreads();
            }
            float bv = A.bih[j] + A.bhh[j];
#pragma unroll
            for (int r = 0; r < 4; ++r) {
                int b = ms * 16 + kq * 4 + r;
                gbuf[(b * 4 + gi) * 8 + (col & 7)] = acc[r] + bv;
            }
            __syncthreads();
            {
                int b = tid >> 3, dd = tid & 7, d = d0 + dd;
                float gI = gbuf[(b * 4 + 0) * 8 + dd];
                float gF = gbuf[(b * 4 + 1) * 8 + dd];
                float gG = gbuf[(b * 4 + 2) * 8 + dd];
                float gO = gbuf[(b * 4 + 3) * 8 + dd];
                float si = sigf(gI), sf = sigf(gF), so = sigf(gO);
                float gg = tanhf(gG);
                float c_old = A.c[b * DECD + d];
                float c_new = sf * c_old + si * gg;
                float h_new = so * tanhf(c_new);
                bool mask = t < A.declen[b];
                float h_prev = bf2f(A.hnext[b * DECD + d]);
                A.c[b * DECD + d] = mask ? c_new : c_old;
                A.hnext[b * DECD + d] = f2bf(mask ? h_new : h_prev);
                A.hallbf[((size_t)t * 64 + b) * DECD + d] = f2bf(h_new);
            }
        }
        gbar(A.bar);
    }
}

// ---------------- fc (MFMA): preds = mask ? hall_bf @ WfcT^T + fc_b : 0 ----------------
__global__ __launch_bounds__(256) void k_fc(const unsigned short* hallbf,
                                            const unsigned short* WfcT,
                                            const float* bias, const int* declen,
                                            float* preds) {
    int nb = blockIdx.x, t = blockIdx.y, tid = threadIdx.x;
    int w = tid >> 6, l = tid & 63;
    int col = l & 15, kq = l >> 4;
    int n_base = nb * 256;
    const unsigned short* Abase = hallbf + (size_t)t * 64 * DECD;
    v4f acc[4][4];
    for (int a = 0; a < 4; ++a) for (int s = 0; s < 4; ++s) acc[a][s] = (v4f){0.f,0.f,0.f,0.f};
    for (int kk = 0; kk < 16; ++kk) {
        int k = kk * 32 + kq * 8;
        v8s af[4], bf[4];
#pragma unroll
        for (int ms = 0; ms < 4; ++ms)
            af[ms] = *(const v8s*)(Abase + (size_t)(ms * 16 + col) * DECD + k);
#pragma unroll
        for (int ss = 0; ss < 4; ++ss)
            bf[ss] = *(const v8s*)(WfcT + (size_t)(n_base + (w * 4 + ss) * 16 + col) * DECD + k);
#pragma unroll
        for (int ms = 0; ms < 4; ++ms)
#pragma unroll
            for (int ss = 0; ss < 4; ++ss)
                acc[ms][ss] = __builtin_amdgcn_mfma_f32_16x16x32_bf16(af[ms], bf[ss], acc[ms][ss], 0, 0, 0);
    }
#pragma unroll
    for (int ms = 0; ms < 4; ++ms)
#pragma unroll
        for (int ss = 0; ss < 4; ++ss) {
            int v = n_base + (w * 4 + ss) * 16 + col;
            if (v < VOC) {
                float bv = bias[v];
#pragma unroll
                for (int r = 0; r < 4; ++r) {
                    int b = ms * 16 + kq * 4 + r;
                    bool mask = t < declen[b];
                    preds[((size_t)b * TSTEPS + t) * VOC + v] =
                        mask ? (acc[ms][ss][r] + bv) : 0.f;
                }
            }
        }
}

extern "C" void kernel_launch(void* const* d_in, const int* in_sizes, int n_in,
                              void* d_out, int out_size, void* d_ws, size_t ws_size,
                              hipStream_t stream) {
    const float* enc      = (const float*)d_in[0];
    const int*   caps     = (const int*)d_in[1];
    const int*   lens     = (const int*)d_in[2];
    const float* embW     = (const float*)d_in[3];
    const float* att_enc_W = (const float*)d_in[4];
    const float* att_enc_b = (const float*)d_in[5];
    const float* att_dec_W = (const float*)d_in[6];
    const float* att_dec_b = (const float*)d_in[7];
    const float* att_full_w = (const float*)d_in[8];
    const float* att_full_b = (const float*)d_in[9];
    const float* lstm_Wih = (const float*)d_in[10];
    const float* lstm_Whh = (const float*)d_in[11];
    const float* lstm_bih = (const float*)d_in[12];
    const float* lstm_bhh = (const float*)d_in[13];
    const float* initH_W  = (const float*)d_in[14];
    const float* initH_b  = (const float*)d_in[15];
    const float* initC_W  = (const float*)d_in[16];
    const float* initC_b  = (const float*)d_in[17];
    const float* fbeta_W  = (const float*)d_in[18];
    const float* fbeta_b  = (const float*)d_in[19];
    const float* fc_W     = (const float*)d_in[20];
    const float* fc_b     = (const float*)d_in[21];

    // outputs (flat f32): preds | caps | dec_len | alphas | order
    float* o = (float*)d_out;
    float* preds_out  = o;
    float* caps_out   = o + (size_t)BATCH * TSTEPS * VOC;
    float* declen_out = caps_out + (size_t)BATCH * LCAP;
    float* order_out  = declen_out + BATCH;
    float* alphas_out = order_out + BATCH;

    // workspace layout
    char* wsb = (char*)d_ws;
    int* i_bar    = (int*)wsb;                  // 2
    int* i_order  = i_bar + 16;                 // 64
    int* i_declen = i_order + 64;               // 64
    float* f = (float*)(wsb + 1024);
    float* f_mean = f;  f += (size_t)BATCH * ENCD;
    float* f_c    = f;  f += (size_t)BATCH * DECD;
    float* f_att2 = f;  f += (size_t)BATCH * ATTD;
    float* f_gate = f;  f += (size_t)BATCH * ENCD;
    f = (float*)(((uintptr_t)f + 255) & ~(uintptr_t)255);
    unsigned short* bf = (unsigned short*)f;
    unsigned short* hnext_bf = bf;  bf += (size_t)BATCH * DECD;
    unsigned short* xh_bf    = bf;  bf += (size_t)BATCH * XHDIM;
    unsigned short* hall_bf  = bf;  bf += (size_t)TSTEPS * BATCH * DECD;
    unsigned short* att1_bf  = bf;  bf += (size_t)BATCH * PIX * ATTD;
    unsigned short* WagT_bf  = bf;  bf += (size_t)AGDIM * DECD;
    unsigned short* attWT_bf = bf;  bf += (size_t)ATTD * ENCD;
    unsigned short* Wcomb_bf = bf;  bf += (size_t)2048 * XHDIM;
    unsigned short* WfcT_bf  = bf;  bf += (size_t)VOCP * DECD;
    bf = (unsigned short*)(((uintptr_t)bf + 255) & ~(uintptr_t)255);
    unsigned short* enc_bf   = bf;  bf += (size_t)BATCH * PIX * ENCD;

    // ---- one-time setup ----
    k_setup<<<1, 64, 0, stream>>>(caps, lens, i_order, i_declen, i_bar,
                                  caps_out, declen_out, order_out);
    // WagT rows 0..511 from att_dec_W (512x512), rows 512..2559 from fbeta_W (512x2048)
    k_tr<<<dim3(8, 8), 256, 0, stream>>>(att_dec_W, DECD, ATTD, WagT_bf, ATTD);
    k_tr<<<dim3(32, 8), 256, 0, stream>>>(fbeta_W, DECD, ENCD,
                                          WagT_bf + (size_t)512 * DECD, ENCD);
    k_tr<<<dim3(8, 32), 256, 0, stream>>>(att_enc_W, ENCD, ATTD, attWT_bf, ATTD);
    k_tr<<<dim3(160, 8), 256, 0, stream>>>(fc_W, DECD, VOC, WfcT_bf, VOCP);
    k_cvt_comb<<<2048, 256, 0, stream>>>(lstm_Wih, lstm_Whh, Wcomb_bf);
    k_cvt_enc<<<dim3(BATCH, PIX), 256, 0, stream>>>(enc, i_order, enc_bf);
    k_mean<<<dim3(BATCH, ENCD / 256), 256, 0, stream>>>(enc, i_order, f_mean);
    k_h0c0<<<16, 256, 0, stream>>>(f_mean, initH_W, initH_b, initC_W, initC_b,
                                   f_c, hnext_bf, xh_bf);
    k_att1<<<dim3(49, 8), 256, 0, stream>>>(enc_bf, attWT_bf, att_enc_b, att1_bf);

    // ---- persistent scan ----
    ScanArgs sa;
    sa.WagT = WagT_bf; sa.Wcomb = Wcomb_bf; sa.att1bf = att1_bf; sa.enc_bf = enc_bf;
    sa.bad = att_dec_b; sa.bfb = fbeta_b; sa.wfull = att_full_w; sa.bfull = att_full_b;
    sa.bih = lstm_bih; sa.bhh = lstm_bhh; sa.embW = embW;
    sa.caps = caps; sa.order = i_order; sa.declen = i_declen;
    sa.hnext = hnext_bf; sa.xh = xh_bf; sa.hallbf = hall_bf;
    sa.att2 = f_att2; sa.gate = f_gate; sa.c = f_c;
    sa.alphas_out = alphas_out;
    sa.bar = i_bar;
    void* kargs[] = { &sa };
    hipLaunchCooperativeKernel((void*)k_scan, dim3(NBLK), dim3(NTHR), kargs, 0, stream);

    // ---- batched fc ----
    k_fc<<<dim3(40, TSTEPS), 256, 0, stream>>>(hall_bf, WfcT_bf, fc_b,
                                               i_declen, preds_out);
}